// Round 12
// baseline (119.101 us; speedup 1.0000x reference)
//
#include <hip/hip_runtime.h>

// Bahdanau additive attention: B=8, TE=512, TD=256, H=256, fp32.
//   We = enc @ W_a; Uh = dec @ U_a
//   e[b,j,i] = softmax_i( sum_h V[h]*tanh(We[b,i,h]+Uh[b,j,h]) )
//   c[b,j,h] = sum_i e[b,j,i]*enc[b,i,h]
// d_out = [c (B*TD*H)] ++ [e (B*TD*TE)]
//
// Identity (R3): tanh(x) = 1 - 2/(1+exp2(Kx)); exp2(K(w+u)) = w~*u~ in the
// exp2 domain -> v_rcp is the only transcendental. 8-way rcp batching (R11).
// R12: (a) phase B reads sP via ds_read_b128 (was 4x ds_read_b32/iter =
// ~10us of shared LDS pipe -- the hidden phase-B bound); (b) phase A 4-deep
// register prefetch pipeline for the W stream (was ~2 in flight vs ~250cyc
// L2 latency); (c) phase B back to fp32 enc (no cvt, no copy pass).
// Keeps: XCD swizzle (b=blockIdx&7), 4 j/block, fp16 W stream, grid 512.
// Dead theories (measured): bytes R11, occupancy R10, instr count R9.
// R5 lesson: no tight VGPR caps like (1024,8) -- spills. (512,4)=128 cap ok.

#define BB 8
#define TE 512
#define TD 256
#define HH 256

#define EXP2F(x) __builtin_amdgcn_exp2f(x)
#define RCPF(x)  __builtin_amdgcn_rcpf(x)
#define KSCALE   2.8853900817779268f    // 2*log2(e)
#define NSC      (-2.8853900817779268f) // -2*log2(e)

typedef _Float16 h4 __attribute__((ext_vector_type(4)));
typedef _Float16 h8 __attribute__((ext_vector_type(8)));

// ---------------------------------------------------------------------------
// k_pre: blocks 0..255: We = enc@Wa -> W4h[b][h/8][i][8] fp16, exp2-domain.
//        blocks 256..383: Uh = dec@Ua -> Uhe[j][h] fp32, exp2-domain.
// GEMM: 64x64 tile, Kc=32, 4x4 per thread (tx=col-quad, ty=row-quad).
// ---------------------------------------------------------------------------
__global__ __launch_bounds__(256) void k_pre(
    const float* __restrict__ enc, const float* __restrict__ dec,
    const float* __restrict__ Wa,  const float* __restrict__ Ua,
    _Float16* __restrict__ W4h, float* __restrict__ Uhe)
{
    const int tid = threadIdx.x;
    const bool is_enc = blockIdx.x < 256;
    const int bi = is_enc ? blockIdx.x : (blockIdx.x - 256);
    const int m0 = (bi >> 2) * 64;
    const int n0 = (bi & 3) * 64;
    const float* X = is_enc ? enc : dec;
    const float* W = is_enc ? Wa : Ua;

    __shared__ float Xs[32][68];
    __shared__ float Ws[32][68];

    const int kq = tid & 7,  xr = tid >> 3;
    const int wk = tid >> 3, wn = (tid & 7) * 8;
    const int tx = tid & 15, ty = tid >> 4;

    float acc[4][4];   // acc[r = row-offset][c = col-offset]
    #pragma unroll
    for (int r = 0; r < 4; r++)
        #pragma unroll
        for (int c = 0; c < 4; c++) acc[r][c] = 0.f;

    for (int kc = 0; kc < HH; kc += 32) {
        float4 xa = *(const float4*)(X + (size_t)(m0 + xr) * HH + kc + kq * 4);
        float4 xb = *(const float4*)(X + (size_t)(m0 + xr + 32) * HH + kc + kq * 4);
        float4 wa = *(const float4*)(W + (size_t)(kc + wk) * HH + n0 + wn);
        float4 wb = *(const float4*)(W + (size_t)(kc + wk) * HH + n0 + wn + 4);
        __syncthreads();
        Xs[kq * 4 + 0][xr] = xa.x; Xs[kq * 4 + 1][xr] = xa.y;
        Xs[kq * 4 + 2][xr] = xa.z; Xs[kq * 4 + 3][xr] = xa.w;
        Xs[kq * 4 + 0][xr + 32] = xb.x; Xs[kq * 4 + 1][xr + 32] = xb.y;
        Xs[kq * 4 + 2][xr + 32] = xb.z; Xs[kq * 4 + 3][xr + 32] = xb.w;
        *(float4*)&Ws[wk][wn]     = wa;
        *(float4*)&Ws[wk][wn + 4] = wb;
        __syncthreads();
        #pragma unroll
        for (int k = 0; k < 32; k++) {
            float4 a = *(const float4*)&Xs[k][ty * 4];   // 4 rows
            float4 b = *(const float4*)&Ws[k][tx * 4];   // 4 cols
            acc[0][0] = fmaf(a.x, b.x, acc[0][0]); acc[0][1] = fmaf(a.x, b.y, acc[0][1]);
            acc[0][2] = fmaf(a.x, b.z, acc[0][2]); acc[0][3] = fmaf(a.x, b.w, acc[0][3]);
            acc[1][0] = fmaf(a.y, b.x, acc[1][0]); acc[1][1] = fmaf(a.y, b.y, acc[1][1]);
            acc[1][2] = fmaf(a.y, b.z, acc[1][2]); acc[1][3] = fmaf(a.y, b.w, acc[1][3]);
            acc[2][0] = fmaf(a.z, b.x, acc[2][0]); acc[2][1] = fmaf(a.z, b.y, acc[2][1]);
            acc[2][2] = fmaf(a.z, b.z, acc[2][2]); acc[2][3] = fmaf(a.z, b.w, acc[2][3]);
            acc[3][0] = fmaf(a.w, b.x, acc[3][0]); acc[3][1] = fmaf(a.w, b.y, acc[3][1]);
            acc[3][2] = fmaf(a.w, b.z, acc[3][2]); acc[3][3] = fmaf(a.w, b.w, acc[3][3]);
        }
    }

    if (is_enc) {
        const int b  = m0 >> 9;                   // batch
        const int ib = (m0 & 511) + ty * 4;       // i base
        const int hh = n0 + tx * 4;               // h base (4 contiguous)
        const int o  = hh >> 3;                   // h-octet
        const int hf = (hh & 7);                  // 0 or 4 within octet
        #pragma unroll
        for (int r = 0; r < 4; r++) {
            h4 v;
            v.x = (_Float16)EXP2F(acc[r][0] * KSCALE);
            v.y = (_Float16)EXP2F(acc[r][1] * KSCALE);
            v.z = (_Float16)EXP2F(acc[r][2] * KSCALE);
            v.w = (_Float16)EXP2F(acc[r][3] * KSCALE);
            *(h4*)(W4h + (((size_t)b * 32 + o) * TE + ib + r) * 8 + hf) = v;
        }
    } else {
        #pragma unroll
        for (int r = 0; r < 4; r++) {
            float4 v;
            v.x = EXP2F(acc[r][0] * KSCALE); v.y = EXP2F(acc[r][1] * KSCALE);
            v.z = EXP2F(acc[r][2] * KSCALE); v.w = EXP2F(acc[r][3] * KSCALE);
            *(float4*)(Uhe + (size_t)(m0 + ty * 4 + r) * HH + n0 + tx * 4) = v;
        }
    }
}

// ---------------------------------------------------------------------------
// k_attn: 512 threads = 8 waves; block owns 4 consecutive j's of ONE batch,
// batch = blockIdx&7 (XCD-local). Phase A: wave w -> i = 64w+lane, 32
// h-octets; 4-deep register prefetch of the fp16 W stream; per octet one
// b128 (8 h) + uniform u/va s_loads; 8-way batched reciprocal per j (4
// independent chains). Softmax: waves 0-3. Phase B: b128 sP reads (LDS-pipe
// fix) + fp32 enc; 32 KB LDS reduce.
// ---------------------------------------------------------------------------
__global__ __launch_bounds__(512, 4) void k_attn(
    const float* __restrict__ enc, const _Float16* __restrict__ W4h,
    const float* __restrict__ Uhe, const float* __restrict__ Va,
    float* __restrict__ out_c, float* __restrict__ out_e)
{
    const int wv = threadIdx.x >> 6, lane = threadIdx.x & 63;
    const int b   = blockIdx.x & 7;           // XCD-local batch
    const int j0  = (blockIdx.x >> 3) * 4;    // 64 j-groups per batch
    const int jj0 = b * TD + j0;              // block-uniform

    __shared__ float sP[4][TE];      // 8 KB: energies -> probabilities
    __shared__ float sR[8][4][HH];   // 32 KB: phase-B partials

    const int i = (wv << 6) + lane;
    const _Float16* wp = W4h + ((size_t)b * 32 * TE + i) * 8;
    const float* ua = Uhe + (size_t)jj0 * HH;   // block-uniform -> s_load
    const float* va = Va;                        // uniform

    float a0 = 0.f, a1 = 0.f, a2 = 0.f, a3 = 0.f;

    // 8-way batched reciprocal for one j: sum_{t=0..7} v_t/(1+w_t*u_t)
#define OSTEP(ACC, UA, UB)                                                \
    {                                                                     \
        float A0 = fmaf(w0, (UA).x, 1.f);                                 \
        float A1 = fmaf(w1, (UA).y, 1.f);                                 \
        float A2 = fmaf(w2, (UA).z, 1.f);                                 \
        float A3 = fmaf(w3, (UA).w, 1.f);                                 \
        float A4 = fmaf(w4, (UB).x, 1.f);                                 \
        float A5 = fmaf(w5, (UB).y, 1.f);                                 \
        float A6 = fmaf(w6, (UB).z, 1.f);                                 \
        float A7 = fmaf(w7, (UB).w, 1.f);                                 \
        float dab = A0 * A1, dcd = A2 * A3;                               \
        float def_ = A4 * A5, dgh = A6 * A7;                              \
        float nab = fmaf(v4a.x, A1, v4a.y * A0);                          \
        float ncd = fmaf(v4a.z, A3, v4a.w * A2);                          \
        float nef = fmaf(v4b.x, A5, v4b.y * A4);                          \
        float ngh = fmaf(v4b.z, A7, v4b.w * A6);                          \
        float den4a = dab * dcd,  den4b = def_ * dgh;                     \
        float num4a = fmaf(nab, dcd, ncd * dab);                          \
        float num4b = fmaf(nef, dgh, ngh * def_);                         \
        float num = fmaf(num4a, den4b, num4b * den4a);                    \
        ACC = fmaf(num, RCPF(den4a * den4b), ACC);                        \
    }

    // ---- Phase A with 4-deep W prefetch ---------------------------------
    h8 w_pf[4];
    #pragma unroll
    for (int k = 0; k < 4; k++)
        w_pf[k] = *(const h8*)(wp + (size_t)k * TE * 8);

    #pragma unroll
    for (int q0 = 0; q0 < 32; q0 += 4) {
        h8 wg[4];
        #pragma unroll
        for (int k = 0; k < 4; k++) wg[k] = w_pf[k];
        #pragma unroll
        for (int k = 0; k < 4; k++) {
            int qq = q0 + 4 + k; if (qq > 31) qq = 31;   // clamped (dup ok)
            w_pf[k] = *(const h8*)(wp + (size_t)qq * TE * 8);
        }
        #pragma unroll
        for (int k = 0; k < 4; k++) {
            const int q = q0 + k;
            float w0 = (float)wg[k][0], w1 = (float)wg[k][1];
            float w2 = (float)wg[k][2], w3 = (float)wg[k][3];
            float w4 = (float)wg[k][4], w5 = (float)wg[k][5];
            float w6 = (float)wg[k][6], w7 = (float)wg[k][7];
            float4 v4a = *(const float4*)(va + 8 * q);       // uniform
            float4 v4b = *(const float4*)(va + 8 * q + 4);
            float4 u0a = *(const float4*)(ua + 8 * q);       // uniform
            float4 u0b = *(const float4*)(ua + 8 * q + 4);
            float4 u1a = *(const float4*)(ua + HH + 8 * q);
            float4 u1b = *(const float4*)(ua + HH + 8 * q + 4);
            float4 u2a = *(const float4*)(ua + 2 * HH + 8 * q);
            float4 u2b = *(const float4*)(ua + 2 * HH + 8 * q + 4);
            float4 u3a = *(const float4*)(ua + 3 * HH + 8 * q);
            float4 u3b = *(const float4*)(ua + 3 * HH + 8 * q + 4);
            OSTEP(a0, u0a, u0b)
            OSTEP(a1, u1a, u1b)
            OSTEP(a2, u2a, u2b)
            OSTEP(a3, u3a, u3b)
        }
    }
#undef OSTEP

    // conflict-free b32 writes (lane-stride 4B), energies in log2 domain
    sP[0][i] = NSC * a0;
    sP[1][i] = NSC * a1;
    sP[2][i] = NSC * a2;
    sP[3][i] = NSC * a3;
    __syncthreads();

    // ---- softmax: wave w in 0..3 handles j0+w ----------------------------
    if (wv < 4) {
        float ev[8];
        float m = -3.0e38f;
        #pragma unroll
        for (int k = 0; k < 8; k++) {
            ev[k] = sP[wv][lane + 64 * k];
            m = fmaxf(m, ev[k]);
        }
        #pragma unroll
        for (int off = 32; off; off >>= 1) m = fmaxf(m, __shfl_xor(m, off, 64));
        float s = 0.f;
        #pragma unroll
        for (int k = 0; k < 8; k++) { ev[k] = EXP2F(ev[k] - m); s += ev[k]; }
        #pragma unroll
        for (int off = 32; off; off >>= 1) s += __shfl_xor(s, off, 64);
        float rs = RCPF(s);
        float* oe = out_e + (size_t)(jj0 + wv) * TE;
        #pragma unroll
        for (int k = 0; k < 8; k++) {
            float p = ev[k] * rs;
            sP[wv][lane + 64 * k] = p;
            oe[lane + 64 * k] = p;
        }
    }
    __syncthreads();

    // ---- Phase B: wave w -> i in [64w, 64w+64), all 4 j ------------------
    // b128 sP reads: 4 ds_read_b128 per 4 i-steps (was 16 ds_read_b32).
    const int ib = wv << 6;
    const float* eb = enc + ((size_t)b * TE + ib) * HH + 4 * lane;
    float4 c0 = {0,0,0,0}, c1 = {0,0,0,0}, c2 = {0,0,0,0}, c3 = {0,0,0,0};
    #pragma unroll 2
    for (int k4 = 0; k4 < 16; k4++) {
        float4 p0 = *(const float4*)&sP[0][ib + 4 * k4];   // uniform b128
        float4 p1 = *(const float4*)&sP[1][ib + 4 * k4];
        float4 p2 = *(const float4*)&sP[2][ib + 4 * k4];
        float4 p3 = *(const float4*)&sP[3][ib + 4 * k4];
        const float* ep = eb + (size_t)k4 * 4 * HH;
        float4 q0 = *(const float4*)(ep);
        float4 q1 = *(const float4*)(ep + HH);
        float4 q2 = *(const float4*)(ep + 2 * HH);
        float4 q3 = *(const float4*)(ep + 3 * HH);
        c0.x = fmaf(p0.x, q0.x, c0.x); c0.y = fmaf(p0.x, q0.y, c0.y);
        c0.z = fmaf(p0.x, q0.z, c0.z); c0.w = fmaf(p0.x, q0.w, c0.w);
        c1.x = fmaf(p1.x, q0.x, c1.x); c1.y = fmaf(p1.x, q0.y, c1.y);
        c1.z = fmaf(p1.x, q0.z, c1.z); c1.w = fmaf(p1.x, q0.w, c1.w);
        c2.x = fmaf(p2.x, q0.x, c2.x); c2.y = fmaf(p2.x, q0.y, c2.y);
        c2.z = fmaf(p2.x, q0.z, c2.z); c2.w = fmaf(p2.x, q0.w, c2.w);
        c3.x = fmaf(p3.x, q0.x, c3.x); c3.y = fmaf(p3.x, q0.y, c3.y);
        c3.z = fmaf(p3.x, q0.z, c3.z); c3.w = fmaf(p3.x, q0.w, c3.w);
        c0.x = fmaf(p0.y, q1.x, c0.x); c0.y = fmaf(p0.y, q1.y, c0.y);
        c0.z = fmaf(p0.y, q1.z, c0.z); c0.w = fmaf(p0.y, q1.w, c0.w);
        c1.x = fmaf(p1.y, q1.x, c1.x); c1.y = fmaf(p1.y, q1.y, c1.y);
        c1.z = fmaf(p1.y, q1.z, c1.z); c1.w = fmaf(p1.y, q1.w, c1.w);
        c2.x = fmaf(p2.y, q1.x, c2.x); c2.y = fmaf(p2.y, q1.y, c2.y);
        c2.z = fmaf(p2.y, q1.z, c2.z); c2.w = fmaf(p2.y, q1.w, c2.w);
        c3.x = fmaf(p3.y, q1.x, c3.x); c3.y = fmaf(p3.y, q1.y, c3.y);
        c3.z = fmaf(p3.y, q1.z, c3.z); c3.w = fmaf(p3.y, q1.w, c3.w);
        c0.x = fmaf(p0.z, q2.x, c0.x); c0.y = fmaf(p0.z, q2.y, c0.y);
        c0.z = fmaf(p0.z, q2.z, c0.z); c0.w = fmaf(p0.z, q2.w, c0.w);
        c1.x = fmaf(p1.z, q2.x, c1.x); c1.y = fmaf(p1.z, q2.y, c1.y);
        c1.z = fmaf(p1.z, q2.z, c1.z); c1.w = fmaf(p1.z, q2.w, c1.w);
        c2.x = fmaf(p2.z, q2.x, c2.x); c2.y = fmaf(p2.z, q2.y, c2.y);
        c2.z = fmaf(p2.z, q2.z, c2.z); c2.w = fmaf(p2.z, q2.w, c2.w);
        c3.x = fmaf(p3.z, q2.x, c3.x); c3.y = fmaf(p3.z, q2.y, c3.y);
        c3.z = fmaf(p3.z, q2.z, c3.z); c3.w = fmaf(p3.z, q2.w, c3.w);
        c0.x = fmaf(p0.w, q3.x, c0.x); c0.y = fmaf(p0.w, q3.y, c0.y);
        c0.z = fmaf(p0.w, q3.z, c0.z); c0.w = fmaf(p0.w, q3.w, c0.w);
        c1.x = fmaf(p1.w, q3.x, c1.x); c1.y = fmaf(p1.w, q3.y, c1.y);
        c1.z = fmaf(p1.w, q3.z, c1.z); c1.w = fmaf(p1.w, q3.w, c1.w);
        c2.x = fmaf(p2.w, q3.x, c2.x); c2.y = fmaf(p2.w, q3.y, c2.y);
        c2.z = fmaf(p2.w, q3.z, c2.z); c2.w = fmaf(p2.w, q3.w, c2.w);
        c3.x = fmaf(p3.w, q3.x, c3.x); c3.y = fmaf(p3.w, q3.y, c3.y);
        c3.z = fmaf(p3.w, q3.z, c3.z); c3.w = fmaf(p3.w, q3.w, c3.w);
    }
    *(float4*)&sR[wv][0][4 * lane] = c0;
    *(float4*)&sR[wv][1][4 * lane] = c1;
    *(float4*)&sR[wv][2][4 * lane] = c2;
    *(float4*)&sR[wv][3][4 * lane] = c3;
    __syncthreads();

    // ---- final reduce: wave w -> (j = w&3, h-half = w>>2) ----------------
    {
        const int jr = wv & 3;
        const int h2 = (wv >> 2) * 128 + 2 * lane;
        float sx = 0.f, sy = 0.f;
        #pragma unroll
        for (int ww = 0; ww < 8; ww++) {
            float2 t = *(const float2*)&sR[ww][jr][h2];
            sx += t.x; sy += t.y;
        }
        float2 o; o.x = sx; o.y = sy;
        *(float2*)(out_c + (size_t)(jj0 + jr) * HH + h2) = o;
    }
}

extern "C" void kernel_launch(void* const* d_in, const int* in_sizes, int n_in,
                              void* d_out, int out_size, void* d_ws, size_t ws_size,
                              hipStream_t stream) {
    const float* enc = (const float*)d_in[0];
    const float* dec = (const float*)d_in[1];
    const float* Wa  = (const float*)d_in[2];
    const float* Ua  = (const float*)d_in[3];
    const float* Va  = (const float*)d_in[4];

    _Float16* W4h = (_Float16*)d_ws;                       // B*H*TE fp16 (2 MB)
    float*    Uhe = (float*)(W4h + (size_t)BB * HH * TE);  // B*TD*H fp32 (2 MB)

    float* out_c = (float*)d_out;                    // [B,TD,H]
    float* out_e = out_c + (size_t)BB * TD * HH;     // [B,TD,TE]

    k_pre<<<384, 256, 0, stream>>>(enc, dec, Wa, Ua, W4h, Uhe);
    k_attn<<<BB * TD / 4, 512, 0, stream>>>(enc, W4h, Uhe, Va, out_c, out_e);
}

// Round 13
// 114.169 us; speedup vs baseline: 1.0432x; 1.0432x over previous
//
#include <hip/hip_runtime.h>

// Bahdanau additive attention: B=8, TE=512, TD=256, H=256, fp32.
//   We = enc @ W_a; Uh = dec @ U_a
//   e[b,j,i] = softmax_i( sum_h V[h]*tanh(We[b,i,h]+Uh[b,j,h]) )
//   c[b,j,h] = sum_i e[b,j,i]*enc[b,i,h]
// d_out = [c (B*TD*H)] ++ [e (B*TD*TE)]
//
// Identity (R3): tanh(x) = 1 - 2/(1+exp2(Kx)); exp2(K(w+u)) = w~*u~ in the
// exp2 domain -> v_rcp is the only transcendental.
// R13 = best-of-each-phase: phase A fp32 W4 stream (R8 layout; fp16+cvt was
// slower, R11) + 8-way rcp batching (30 full-rate + 1 rcp / 8 elems) + plain
// unroll-2 (R12's explicit prefetch ADDED ~9us VALU); phase B ds_read_b128
// sP reads (R12's win). XCD swizzle (b=blockIdx&7), 4 j/block, grid 512.
// Dead theories (measured): bytes R11, occupancy R10, instr count R9,
// explicit prefetch R12. R5: no tight VGPR caps.

#define BB 8
#define TE 512
#define TD 256
#define HH 256

#define EXP2F(x) __builtin_amdgcn_exp2f(x)
#define RCPF(x)  __builtin_amdgcn_rcpf(x)
#define KSCALE   2.8853900817779268f    // 2*log2(e)
#define NSC      (-2.8853900817779268f) // -2*log2(e)

// ---------------------------------------------------------------------------
// k_pre: C = [enc;dec] @ [Wa|Ua]; store exp2(KSCALE*C).
// Blocks 0..255: enc -> W4[b][h/4][i][4] (interleaved-transposed).
// Blocks 256..383: dec -> Uhe[j][h] (direct).
// 64x64 tile, Kc=32, 4x4 per thread (tx=col-quad, ty=row-quad).
// ---------------------------------------------------------------------------
__global__ __launch_bounds__(256) void k_pre(
    const float* __restrict__ enc, const float* __restrict__ dec,
    const float* __restrict__ Wa,  const float* __restrict__ Ua,
    float* __restrict__ W4, float* __restrict__ Uhe)
{
    const int tid = threadIdx.x;
    const bool is_enc = blockIdx.x < 256;
    const int bi = is_enc ? blockIdx.x : (blockIdx.x - 256);
    const int m0 = (bi >> 2) * 64;
    const int n0 = (bi & 3) * 64;
    const float* X = is_enc ? enc : dec;
    const float* W = is_enc ? Wa : Ua;

    __shared__ float Xs[32][68];
    __shared__ float Ws[32][68];

    const int kq = tid & 7,  xr = tid >> 3;
    const int wk = tid >> 3, wn = (tid & 7) * 8;
    const int tx = tid & 15, ty = tid >> 4;

    float acc[4][4];   // acc[r = row-offset][c = col-offset]
    #pragma unroll
    for (int r = 0; r < 4; r++)
        #pragma unroll
        for (int c = 0; c < 4; c++) acc[r][c] = 0.f;

    for (int kc = 0; kc < HH; kc += 32) {
        float4 xa = *(const float4*)(X + (size_t)(m0 + xr) * HH + kc + kq * 4);
        float4 xb = *(const float4*)(X + (size_t)(m0 + xr + 32) * HH + kc + kq * 4);
        float4 wa = *(const float4*)(W + (size_t)(kc + wk) * HH + n0 + wn);
        float4 wb = *(const float4*)(W + (size_t)(kc + wk) * HH + n0 + wn + 4);
        __syncthreads();
        Xs[kq * 4 + 0][xr] = xa.x; Xs[kq * 4 + 1][xr] = xa.y;
        Xs[kq * 4 + 2][xr] = xa.z; Xs[kq * 4 + 3][xr] = xa.w;
        Xs[kq * 4 + 0][xr + 32] = xb.x; Xs[kq * 4 + 1][xr + 32] = xb.y;
        Xs[kq * 4 + 2][xr + 32] = xb.z; Xs[kq * 4 + 3][xr + 32] = xb.w;
        *(float4*)&Ws[wk][wn]     = wa;
        *(float4*)&Ws[wk][wn + 4] = wb;
        __syncthreads();
        #pragma unroll
        for (int k = 0; k < 32; k++) {
            float4 a = *(const float4*)&Xs[k][ty * 4];   // 4 rows
            float4 b = *(const float4*)&Ws[k][tx * 4];   // 4 cols
            acc[0][0] = fmaf(a.x, b.x, acc[0][0]); acc[0][1] = fmaf(a.x, b.y, acc[0][1]);
            acc[0][2] = fmaf(a.x, b.z, acc[0][2]); acc[0][3] = fmaf(a.x, b.w, acc[0][3]);
            acc[1][0] = fmaf(a.y, b.x, acc[1][0]); acc[1][1] = fmaf(a.y, b.y, acc[1][1]);
            acc[1][2] = fmaf(a.y, b.z, acc[1][2]); acc[1][3] = fmaf(a.y, b.w, acc[1][3]);
            acc[2][0] = fmaf(a.z, b.x, acc[2][0]); acc[2][1] = fmaf(a.z, b.y, acc[2][1]);
            acc[2][2] = fmaf(a.z, b.z, acc[2][2]); acc[2][3] = fmaf(a.z, b.w, acc[2][3]);
            acc[3][0] = fmaf(a.w, b.x, acc[3][0]); acc[3][1] = fmaf(a.w, b.y, acc[3][1]);
            acc[3][2] = fmaf(a.w, b.z, acc[3][2]); acc[3][3] = fmaf(a.w, b.w, acc[3][3]);
        }
    }

    if (is_enc) {
        const int b  = m0 >> 9;                  // batch
        const int ib = (m0 & 511) + ty * 4;      // i base
        const int hq = (n0 >> 2) + tx;           // h-quad
        float* dst = W4 + (((size_t)b * 64 + hq) * TE + ib) * 4;
        #pragma unroll
        for (int r = 0; r < 4; r++) {
            float4 v;
            v.x = EXP2F(acc[r][0] * KSCALE); v.y = EXP2F(acc[r][1] * KSCALE);
            v.z = EXP2F(acc[r][2] * KSCALE); v.w = EXP2F(acc[r][3] * KSCALE);
            *(float4*)(dst + (size_t)r * 4) = v;
        }
    } else {
        #pragma unroll
        for (int r = 0; r < 4; r++) {
            float4 v;
            v.x = EXP2F(acc[r][0] * KSCALE); v.y = EXP2F(acc[r][1] * KSCALE);
            v.z = EXP2F(acc[r][2] * KSCALE); v.w = EXP2F(acc[r][3] * KSCALE);
            *(float4*)(Uhe + (size_t)(m0 + ty * 4 + r) * HH + n0 + tx * 4) = v;
        }
    }
}

// ---------------------------------------------------------------------------
// k_attn: 512 threads = 8 waves; block owns 4 consecutive j's of ONE batch,
// batch = blockIdx&7 (XCD-local). Phase A: wave w -> i = 64w+lane, 32
// h-octets; per octet TWO b128 fp32 W4 loads (8 h) + uniform u/va s_loads;
// 8-way batched reciprocal per j (4 independent chains). Softmax: waves 0-3.
// Phase B: b128 sP reads + fp32 enc; 32 KB LDS reduce.
// ---------------------------------------------------------------------------
__global__ __launch_bounds__(512) void k_attn(
    const float* __restrict__ enc, const float* __restrict__ W4,
    const float* __restrict__ Uhe, const float* __restrict__ Va,
    float* __restrict__ out_c, float* __restrict__ out_e)
{
    const int wv = threadIdx.x >> 6, lane = threadIdx.x & 63;
    const int b   = blockIdx.x & 7;           // XCD-local batch
    const int j0  = (blockIdx.x >> 3) * 4;    // 64 j-groups per batch
    const int jj0 = b * TD + j0;              // block-uniform

    __shared__ float sP[4][TE];      // 8 KB: energies -> probabilities
    __shared__ float sR[8][4][HH];   // 32 KB: phase-B partials

    const int i = (wv << 6) + lane;
    const float* wp = W4 + ((size_t)b * 64 * TE + i) * 4;
    const float* ua = Uhe + (size_t)jj0 * HH;   // block-uniform -> s_load
    const float* va = Va;                        // uniform

    float a0 = 0.f, a1 = 0.f, a2 = 0.f, a3 = 0.f;

    // 8-way batched reciprocal for one j: sum_{t=0..7} v_t/(1+w_t*u_t)
#define OSTEP(ACC, UA, UB)                                                \
    {                                                                     \
        float A0 = fmaf(wa.x, (UA).x, 1.f);                               \
        float A1 = fmaf(wa.y, (UA).y, 1.f);                               \
        float A2 = fmaf(wa.z, (UA).z, 1.f);                               \
        float A3 = fmaf(wa.w, (UA).w, 1.f);                               \
        float A4 = fmaf(wb.x, (UB).x, 1.f);                               \
        float A5 = fmaf(wb.y, (UB).y, 1.f);                               \
        float A6 = fmaf(wb.z, (UB).z, 1.f);                               \
        float A7 = fmaf(wb.w, (UB).w, 1.f);                               \
        float dab = A0 * A1, dcd = A2 * A3;                               \
        float def_ = A4 * A5, dgh = A6 * A7;                              \
        float nab = fmaf(v4a.x, A1, v4a.y * A0);                          \
        float ncd = fmaf(v4a.z, A3, v4a.w * A2);                          \
        float nef = fmaf(v4b.x, A5, v4b.y * A4);                          \
        float ngh = fmaf(v4b.z, A7, v4b.w * A6);                          \
        float den4a = dab * dcd,  den4b = def_ * dgh;                     \
        float num4a = fmaf(nab, dcd, ncd * dab);                          \
        float num4b = fmaf(nef, dgh, ngh * def_);                         \
        float num = fmaf(num4a, den4b, num4b * den4a);                    \
        ACC = fmaf(num, RCPF(den4a * den4b), ACC);                        \
    }

    #pragma unroll 2
    for (int q = 0; q < 32; q++) {
        float4 wa = *(const float4*)(wp + (size_t)(2 * q) * TE * 4);
        float4 wb = *(const float4*)(wp + (size_t)(2 * q + 1) * TE * 4);
        float4 v4a = *(const float4*)(va + 8 * q);       // uniform
        float4 v4b = *(const float4*)(va + 8 * q + 4);
        float4 u0a = *(const float4*)(ua + 8 * q);       // uniform
        float4 u0b = *(const float4*)(ua + 8 * q + 4);
        float4 u1a = *(const float4*)(ua + HH + 8 * q);
        float4 u1b = *(const float4*)(ua + HH + 8 * q + 4);
        float4 u2a = *(const float4*)(ua + 2 * HH + 8 * q);
        float4 u2b = *(const float4*)(ua + 2 * HH + 8 * q + 4);
        float4 u3a = *(const float4*)(ua + 3 * HH + 8 * q);
        float4 u3b = *(const float4*)(ua + 3 * HH + 8 * q + 4);
        OSTEP(a0, u0a, u0b)
        OSTEP(a1, u1a, u1b)
        OSTEP(a2, u2a, u2b)
        OSTEP(a3, u3a, u3b)
    }
#undef OSTEP

    // conflict-free b32 writes (lane-stride 4B), energies in log2 domain
    sP[0][i] = NSC * a0;
    sP[1][i] = NSC * a1;
    sP[2][i] = NSC * a2;
    sP[3][i] = NSC * a3;
    __syncthreads();

    // ---- softmax: wave w in 0..3 handles j0+w ----------------------------
    if (wv < 4) {
        float ev[8];
        float m = -3.0e38f;
        #pragma unroll
        for (int k = 0; k < 8; k++) {
            ev[k] = sP[wv][lane + 64 * k];
            m = fmaxf(m, ev[k]);
        }
        #pragma unroll
        for (int off = 32; off; off >>= 1) m = fmaxf(m, __shfl_xor(m, off, 64));
        float s = 0.f;
        #pragma unroll
        for (int k = 0; k < 8; k++) { ev[k] = EXP2F(ev[k] - m); s += ev[k]; }
        #pragma unroll
        for (int off = 32; off; off >>= 1) s += __shfl_xor(s, off, 64);
        float rs = RCPF(s);
        float* oe = out_e + (size_t)(jj0 + wv) * TE;
        #pragma unroll
        for (int k = 0; k < 8; k++) {
            float p = ev[k] * rs;
            sP[wv][lane + 64 * k] = p;
            oe[lane + 64 * k] = p;
        }
    }
    __syncthreads();

    // ---- Phase B: wave w -> i in [64w, 64w+64), all 4 j ------------------
    // b128 sP reads: 4 ds_read_b128 per 4 i-steps (R12's LDS-pipe fix).
    const int ib = wv << 6;
    const float* eb = enc + ((size_t)b * TE + ib) * HH + 4 * lane;
    float4 c0 = {0,0,0,0}, c1 = {0,0,0,0}, c2 = {0,0,0,0}, c3 = {0,0,0,0};
    #pragma unroll 2
    for (int k4 = 0; k4 < 16; k4++) {
        float4 p0 = *(const float4*)&sP[0][ib + 4 * k4];   // uniform b128
        float4 p1 = *(const float4*)&sP[1][ib + 4 * k4];
        float4 p2 = *(const float4*)&sP[2][ib + 4 * k4];
        float4 p3 = *(const float4*)&sP[3][ib + 4 * k4];
        const float* ep = eb + (size_t)k4 * 4 * HH;
        float4 q0 = *(const float4*)(ep);
        float4 q1 = *(const float4*)(ep + HH);
        float4 q2 = *(const float4*)(ep + 2 * HH);
        float4 q3 = *(const float4*)(ep + 3 * HH);
        c0.x = fmaf(p0.x, q0.x, c0.x); c0.y = fmaf(p0.x, q0.y, c0.y);
        c0.z = fmaf(p0.x, q0.z, c0.z); c0.w = fmaf(p0.x, q0.w, c0.w);
        c1.x = fmaf(p1.x, q0.x, c1.x); c1.y = fmaf(p1.x, q0.y, c1.y);
        c1.z = fmaf(p1.x, q0.z, c1.z); c1.w = fmaf(p1.x, q0.w, c1.w);
        c2.x = fmaf(p2.x, q0.x, c2.x); c2.y = fmaf(p2.x, q0.y, c2.y);
        c2.z = fmaf(p2.x, q0.z, c2.z); c2.w = fmaf(p2.x, q0.w, c2.w);
        c3.x = fmaf(p3.x, q0.x, c3.x); c3.y = fmaf(p3.x, q0.y, c3.y);
        c3.z = fmaf(p3.x, q0.z, c3.z); c3.w = fmaf(p3.x, q0.w, c3.w);
        c0.x = fmaf(p0.y, q1.x, c0.x); c0.y = fmaf(p0.y, q1.y, c0.y);
        c0.z = fmaf(p0.y, q1.z, c0.z); c0.w = fmaf(p0.y, q1.w, c0.w);
        c1.x = fmaf(p1.y, q1.x, c1.x); c1.y = fmaf(p1.y, q1.y, c1.y);
        c1.z = fmaf(p1.y, q1.z, c1.z); c1.w = fmaf(p1.y, q1.w, c1.w);
        c2.x = fmaf(p2.y, q1.x, c2.x); c2.y = fmaf(p2.y, q1.y, c2.y);
        c2.z = fmaf(p2.y, q1.z, c2.z); c2.w = fmaf(p2.y, q1.w, c2.w);
        c3.x = fmaf(p3.y, q1.x, c3.x); c3.y = fmaf(p3.y, q1.y, c3.y);
        c3.z = fmaf(p3.y, q1.z, c3.z); c3.w = fmaf(p3.y, q1.w, c3.w);
        c0.x = fmaf(p0.z, q2.x, c0.x); c0.y = fmaf(p0.z, q2.y, c0.y);
        c0.z = fmaf(p0.z, q2.z, c0.z); c0.w = fmaf(p0.z, q2.w, c0.w);
        c1.x = fmaf(p1.z, q2.x, c1.x); c1.y = fmaf(p1.z, q2.y, c1.y);
        c1.z = fmaf(p1.z, q2.z, c1.z); c1.w = fmaf(p1.z, q2.w, c1.w);
        c2.x = fmaf(p2.z, q2.x, c2.x); c2.y = fmaf(p2.z, q2.y, c2.y);
        c2.z = fmaf(p2.z, q2.z, c2.z); c2.w = fmaf(p2.z, q2.w, c2.w);
        c3.x = fmaf(p3.z, q2.x, c3.x); c3.y = fmaf(p3.z, q2.y, c3.y);
        c3.z = fmaf(p3.z, q2.z, c3.z); c3.w = fmaf(p3.z, q2.w, c3.w);
        c0.x = fmaf(p0.w, q3.x, c0.x); c0.y = fmaf(p0.w, q3.y, c0.y);
        c0.z = fmaf(p0.w, q3.z, c0.z); c0.w = fmaf(p0.w, q3.w, c0.w);
        c1.x = fmaf(p1.w, q3.x, c1.x); c1.y = fmaf(p1.w, q3.y, c1.y);
        c1.z = fmaf(p1.w, q3.z, c1.z); c1.w = fmaf(p1.w, q3.w, c1.w);
        c2.x = fmaf(p2.w, q3.x, c2.x); c2.y = fmaf(p2.w, q3.y, c2.y);
        c2.z = fmaf(p2.w, q3.z, c2.z); c2.w = fmaf(p2.w, q3.w, c2.w);
        c3.x = fmaf(p3.w, q3.x, c3.x); c3.y = fmaf(p3.w, q3.y, c3.y);
        c3.z = fmaf(p3.w, q3.z, c3.z); c3.w = fmaf(p3.w, q3.w, c3.w);
    }
    *(float4*)&sR[wv][0][4 * lane] = c0;
    *(float4*)&sR[wv][1][4 * lane] = c1;
    *(float4*)&sR[wv][2][4 * lane] = c2;
    *(float4*)&sR[wv][3][4 * lane] = c3;
    __syncthreads();

    // ---- final reduce: wave w -> (j = w&3, h-half = w>>2) ----------------
    {
        const int jr = wv & 3;
        const int h2 = (wv >> 2) * 128 + 2 * lane;
        float sx = 0.f, sy = 0.f;
        #pragma unroll
        for (int ww = 0; ww < 8; ww++) {
            float2 t = *(const float2*)&sR[ww][jr][h2];
            sx += t.x; sy += t.y;
        }
        float2 o; o.x = sx; o.y = sy;
        *(float2*)(out_c + (size_t)(jj0 + jr) * HH + h2) = o;
    }
}

extern "C" void kernel_launch(void* const* d_in, const int* in_sizes, int n_in,
                              void* d_out, int out_size, void* d_ws, size_t ws_size,
                              hipStream_t stream) {
    const float* enc = (const float*)d_in[0];
    const float* dec = (const float*)d_in[1];
    const float* Wa  = (const float*)d_in[2];
    const float* Ua  = (const float*)d_in[3];
    const float* Va  = (const float*)d_in[4];

    float* W4  = (float*)d_ws;                       // exp2-domain, i-interleaved
    float* Uhe = W4 + (size_t)BB * HH * TE;          // exp2-domain, B*TD*H

    float* out_c = (float*)d_out;                    // [B,TD,H]
    float* out_e = out_c + (size_t)BB * TD * HH;     // [B,TD,TE]

    k_pre<<<384, 256, 0, stream>>>(enc, dec, Wa, Ua, W4, Uhe);
    k_attn<<<BB * TD / 4, 512, 0, stream>>>(enc, W4, Uhe, Va, out_c, out_e);
}